// Round 8
// baseline (63.576 us; speedup 1.0000x reference)
//
#include <hip/hip_runtime.h>

// CrossAttention MI355X — round 11: R4 attn math, 2-wave blocks for occupancy.
// attn grid (64,16) x 128 threads: 4-5 independent barrier domains per CU
// (was 2 lockstep 4-wave blocks) -> one block's __syncthreads vmcnt-drain is
// covered by the other blocks' compute. Per-wave math/staging byte-identical
// to the verified 62.2µs R4 kernel; + s_setprio(1) around compute (T5).
// B=2, C=256, H=W=64 -> N=4096 q-tokens; kv pooled -> Nk=1024. HEADS=8, HDIM=32.

#define CDIM   256
#define NTOK   4096
#define NKTOK  1024
#define HDIM   32
// ATTN_SCALE * log2(e): exp(x*s) = 2^(x*s*log2e); fold into Q projection.
#define QSCALE 0.2550530290582177f
#define LN_EPS 1e-5f

typedef __attribute__((ext_vector_type(8))) short bf16x8;
typedef __attribute__((ext_vector_type(4))) float f32x4;
typedef __attribute__((ext_vector_type(4))) uint u32x4;

__device__ __forceinline__ ushort f2bf(float f) {
  uint u = __builtin_bit_cast(uint, f);
  u += 0x7fff + ((u >> 16) & 1);
  return (ushort)(u >> 16);
}

__device__ __forceinline__ float fast_exp2(float x) {
  float r;
  asm("v_exp_f32 %0, %1" : "=v"(r) : "v"(x));
  return r;
}

__device__ __forceinline__ uint cvt_pk_bf16(float lo, float hi) {
  uint r;
  asm("v_cvt_pk_bf16_f32 %0, %1, %2" : "=v"(r) : "v"(lo), "v"(hi));
  return r;
}

__device__ __forceinline__ void gload_lds16(const void* g, void* l) {
  __builtin_amdgcn_global_load_lds(
      (const __attribute__((address_space(1))) unsigned int*)g,
      (__attribute__((address_space(3))) unsigned int*)l, 16, 0, 0);
}

// ================= prep: weight fp32 -> bf16 only (256 blocks) =================
__global__ __launch_bounds__(256) void prep_kernel(
    const float* __restrict__ wq, const float* __restrict__ wk,
    const float* __restrict__ wvv, const float* __restrict__ wp,
    ushort* __restrict__ wq_bf, ushort* __restrict__ wk_bf,
    ushort* __restrict__ wv_bf, ushort* __restrict__ wp_bf) {
  const int bid = blockIdx.x;
  const int mat = bid >> 6;
  const int base = (bid & 63) * 1024 + threadIdx.x * 4;
  const float* s; ushort* d;
  switch (mat) {
    case 0: s = wq; d = wq_bf; break;
    case 1: s = wk; d = wk_bf; break;
    case 2: s = wvv; d = wv_bf; break;
    default: s = wp; d = wp_bf; break;
  }
  const float4 v = *reinterpret_cast<const float4*>(s + base);
  uint2 pk;
  pk.x = (uint)f2bf(v.x) | ((uint)f2bf(v.y) << 16);
  pk.y = (uint)f2bf(v.z) | ((uint)f2bf(v.w) << 16);
  *reinterpret_cast<uint2*>(d + base) = pk;
}

// ================= fused LN + QKV projection =================
// blocks: [0,256) Q (M=8192), [256,320) K (M=2048), [320,384) V (M=2048).
// Phase 1: block LNs its own 32 tokens (Q: plain LN; K/V: 2x2 avg-pool + LN)
//   into LDS xs[32][264] bf16. Phase 2: proven 4-wave MFMA loop; epilogue
//   identical to R4 (Qp scaled / kvp fragment-tile pack).
__global__ __launch_bounds__(256) void qkv_kernel(
    const float* __restrict__ q_feat, const float* __restrict__ kv_feat,
    const float* __restrict__ nqw, const float* __restrict__ nqb,
    const float* __restrict__ nkw, const float* __restrict__ nkb,
    const ushort* __restrict__ wq_bf, const ushort* __restrict__ wk_bf,
    const ushort* __restrict__ wv_bf,
    const float* __restrict__ bq, const float* __restrict__ bk,
    const float* __restrict__ bv,
    ushort* __restrict__ Qp, ushort* __restrict__ kvp) {
  __shared__ ushort xs[32][264];
  __shared__ float red[2][256];
  __shared__ float stat[2][32];

  const int bid = blockIdx.x;
  int seg, sb;
  const ushort* W; const float* bias;
  if (bid < 256)      { seg = 0; sb = bid;       W = wq_bf; bias = bq; }
  else if (bid < 320) { seg = 1; sb = bid - 256; W = wk_bf; bias = bk; }
  else                { seg = 2; sb = bid - 320; W = wv_bf; bias = bv; }

  const int tid = threadIdx.x;
  const int tok = tid & 31, cg = tid >> 5;      // 8 groups x 32 channels
  const int r0g = sb * 32;

  // ---- phase 1: LN / pool+LN of this block's 32 tokens -> xs ----
  float vals[32];
  float s = 0.f, ss = 0.f;
  if (seg == 0) {
    const int b = r0g >> 12;
    const int n = (r0g & 4095) + tok;
    const float* src = q_feat + (size_t)(b * CDIM + cg * 32) * NTOK + n;
#pragma unroll
    for (int ci = 0; ci < 32; ++ci) {
      const float v = src[(size_t)ci * NTOK];
      vals[ci] = v; s += v; ss = fmaf(v, v, ss);
    }
  } else {
    const int b = r0g >> 10;
    const int hk = (r0g & 1023) >> 5;           // 32 tokens/block -> hk uniform
    const float* src = kv_feat + (size_t)(b * CDIM + cg * 32) * NTOK + hk * 128 + tok * 2;
#pragma unroll
    for (int ci = 0; ci < 32; ++ci) {
      const float* p = src + (size_t)ci * NTOK;
      const float2 a0 = *reinterpret_cast<const float2*>(p);
      const float2 a1 = *reinterpret_cast<const float2*>(p + 64);
      const float v = 0.25f * ((a0.x + a0.y) + (a1.x + a1.y));
      vals[ci] = v; s += v; ss = fmaf(v, v, ss);
    }
  }
  red[0][tid] = s; red[1][tid] = ss;
  __syncthreads();
  if (tid < 32) {
    float st = 0.f, sst = 0.f;
#pragma unroll
    for (int k = 0; k < 8; ++k) { st += red[0][k * 32 + tid]; sst += red[1][k * 32 + tid]; }
    const float mu = st * (1.f / 256.f);
    const float var = sst * (1.f / 256.f) - mu * mu;
    stat[0][tid] = mu; stat[1][tid] = rsqrtf(var + LN_EPS);
  }
  __syncthreads();
  {
    const float mu = stat[0][tok], rs = stat[1][tok];
    const float* lw = (seg == 0) ? nqw : nkw;
    const float* lb = (seg == 0) ? nqb : nkb;
#pragma unroll
    for (int ci = 0; ci < 32; ci += 4) {
      ushort h[4];
#pragma unroll
      for (int j2 = 0; j2 < 4; ++j2) {
        const int c = cg * 32 + ci + j2;
        h[j2] = f2bf(fmaf((vals[ci + j2] - mu) * rs, lw[c], lb[c]));
      }
      uint2 pk2;
      pk2.x = (uint)h[0] | ((uint)h[1] << 16);
      pk2.y = (uint)h[2] | ((uint)h[3] << 16);
      *reinterpret_cast<uint2*>(&xs[tok][cg * 32 + ci]) = pk2;
    }
  }
  __syncthreads();

  // ---- phase 2: projection (proven MFMA loop; A from LDS) ----
  const int lane = tid & 63;
  const int wvi = tid >> 6;
  const int nlan = lane & 15, g = lane >> 4;
  const int rowgrp = wvi >> 1, colh = wvi & 1;
  const int lrow = rowgrp * 16 + nlan;
  const int r0 = r0g + rowgrp * 16;

  f32x4 acc[8];
#pragma unroll
  for (int nt = 0; nt < 8; ++nt) acc[nt] = (f32x4){0.f, 0.f, 0.f, 0.f};

  const ushort* wp = W + (size_t)(colh * 128 + nlan) * CDIM + g * 8;
#pragma unroll
  for (int k0 = 0; k0 < 8; ++k0) {
    const bf16x8 a = *reinterpret_cast<const bf16x8*>(&xs[lrow][g * 8 + k0 * 32]);
#pragma unroll
    for (int nt = 0; nt < 8; ++nt) {
      const bf16x8 bfr = *reinterpret_cast<const bf16x8*>(wp + (size_t)nt * 16 * CDIM + k0 * 32);
      acc[nt] = __builtin_amdgcn_mfma_f32_16x16x32_bf16(a, bfr, acc[nt], 0, 0, 0);
    }
  }

#pragma unroll
  for (int nt = 0; nt < 8; ++nt) {
    const int j = colh * 128 + nt * 16 + nlan;
    const float bj = bias[j];
#pragma unroll
    for (int reg = 0; reg < 4; ++reg) {
      const int r = r0 + 4 * g + reg;
      const float v = acc[nt][reg] + bj;
      if (seg == 0) {
        Qp[(size_t)r * CDIM + j] = f2bf(v * QSCALE);
      } else if (seg == 1) {
        // K -> pack. r = b*1024 + key, j = h*32 + d.
        const int bb = r >> 10, k = r & 1023;
        const int kc = k >> 7, kk = k & 127;
        const int m = kk >> 5, w = kk & 31;
        const int t = 2 * m + ((w >> 2) & 1);
        const int rr = ((w >> 3) << 2) | (w & 3);
        const int hh = j >> 5, d = j & 31;
        kvp[(((size_t)((bb * 8 + hh) * 8 + kc) * 16 + t) << 9) +
            ((d >> 3) * 16 + rr) * 8 + (d & 7)] = f2bf(v);
      } else {
        // V -> pack. r = b*1024 + key, j = h*32 + d.
        const int bb = r >> 10, mk = r & 1023;
        const int hh = j >> 5, d = j & 31;
        const int dt = d >> 4, rr = d & 15;
        const int kc = mk >> 7, km = mk & 127;
        const int ks = km >> 5, w = km & 31;
        const int gq = w >> 3, jj = w & 7;
        kvp[(((size_t)((bb * 8 + hh) * 8 + kc) * 16 + (8 + dt * 4 + ks)) << 9) +
            (gq * 16 + rr) * 8 + jj] = f2bf(v);
      }
    }
  }
}

// ================= attention =================
// grid (64, 16): x = 64-query tile (2 waves x 32 q), y = b*8+h. 128 threads.
// LDS 32KB -> 4-5 blocks/CU co-resident, independent barrier domains.
// Per 128-key chunk: 16KB contiguous staged via global_load_lds from the
// pre-tiled kvp pack (wave wvi stages tiles wvi*8..wvi*8+7, lane l -> +l*16B).
// Swapped QK^T -> register softmax -> PV from registers (verified R4 math).
__global__ __launch_bounds__(128) void attn_kernel(const ushort* __restrict__ Qp,
                                                   const ushort* __restrict__ kvp,
                                                   ushort* __restrict__ aout) {
  __shared__ __align__(16) ushort kvf[2][16][512];
  const int lane = threadIdx.x & 63;
  const int wvi = threadIdx.x >> 6;         // 0..1
  const int nlan = lane & 15, g = lane >> 4;
  const int bh = blockIdx.y;
  const int b = bh >> 3, h = bh & 7;
  const int n0 = blockIdx.x * 64 + wvi * 32;

  bf16x8 qf[2];
#pragma unroll
  for (int qt = 0; qt < 2; ++qt)
    qf[qt] = *reinterpret_cast<const bf16x8*>(
        Qp + (size_t)(b * NTOK + n0 + qt * 16 + nlan) * CDIM + h * HDIM + g * 8);

  const ushort* kvb = kvp + ((size_t)bh << 16);   // 8 chunks x 16 tiles x 512

  auto stage = [&](int buf, int kc_idx) {
    const ushort* cb = kvb + ((size_t)kc_idx << 13);
#pragma unroll
    for (int i = 0; i < 8; ++i) {
      const int t = wvi * 8 + i;
      gload_lds16(cb + t * 512 + lane * 8, &kvf[buf][t][0]);
    }
  };

  f32x4 acc[2][2];
#pragma unroll
  for (int qt = 0; qt < 2; ++qt) {
    acc[qt][0] = (f32x4){0.f, 0.f, 0.f, 0.f};
    acc[qt][1] = (f32x4){0.f, 0.f, 0.f, 0.f};
  }
  float lsum[2] = {0.f, 0.f};
  const f32x4 zero = {0.f, 0.f, 0.f, 0.f};

  stage(0, 0);
  for (int c = 0; c < 8; ++c) {
    const int buf = c & 1;
    __syncthreads();                    // chunk c staged & visible
    if (c < 7) stage(buf ^ 1, c + 1);

    __builtin_amdgcn_s_setprio(1);
#pragma unroll
    for (int m = 0; m < 4; ++m) {       // 32-key block
      uint pk[2][4];                    // [qt][4 packed uints = keys 8g+0..7]
#pragma unroll
      for (int half = 0; half < 2; ++half) {
        const bf16x8 kf = *reinterpret_cast<const bf16x8*>(&kvf[buf][2 * m + half][lane * 8]);
#pragma unroll
        for (int qt = 0; qt < 2; ++qt) {
          const f32x4 s = __builtin_amdgcn_mfma_f32_16x16x32_bf16(kf, qf[qt], zero, 0, 0, 0);
          const float p0 = fast_exp2(s[0]), p1 = fast_exp2(s[1]);
          const float p2 = fast_exp2(s[2]), p3 = fast_exp2(s[3]);
          lsum[qt] += (p0 + p1) + (p2 + p3);
          pk[qt][half * 2 + 0] = cvt_pk_bf16(p0, p1);
          pk[qt][half * 2 + 1] = cvt_pk_bf16(p2, p3);
        }
      }
#pragma unroll
      for (int qt = 0; qt < 2; ++qt) {
        const u32x4 w = {pk[qt][0], pk[qt][1], pk[qt][2], pk[qt][3]};
        const bf16x8 af = __builtin_bit_cast(bf16x8, w);
#pragma unroll
        for (int dt = 0; dt < 2; ++dt) {
          const bf16x8 vf = *reinterpret_cast<const bf16x8*>(&kvf[buf][8 + dt * 4 + m][lane * 8]);
          acc[qt][dt] = __builtin_amdgcn_mfma_f32_16x16x32_bf16(af, vf, acc[qt][dt], 0, 0, 0);
        }
      }
    }
    __builtin_amdgcn_s_setprio(0);
  }

  // lsum per lane covers q = nlan, keys {8g..8g+7} over all blocks; reduce over g.
#pragma unroll
  for (int qt = 0; qt < 2; ++qt) {
    lsum[qt] += __shfl_xor(lsum[qt], 16);
    lsum[qt] += __shfl_xor(lsum[qt], 32);
  }

  ushort* dst = aout + (size_t)(b * NTOK + n0) * CDIM + h * HDIM;
#pragma unroll
  for (int qt = 0; qt < 2; ++qt) {
#pragma unroll
    for (int reg = 0; reg < 4; ++reg) {
      // acc row = q-row 4g+reg; its denominator lives at lane 4g+reg (nlan match).
      const float inv = 1.f / __shfl(lsum[qt], 4 * g + reg);
      const size_t row = (size_t)(qt * 16 + 4 * g + reg) * CDIM;
      dst[row + nlan] = f2bf(acc[qt][0][reg] * inv);
      dst[row + 16 + nlan] = f2bf(acc[qt][1][reg] * inv);
    }
  }
}

// ================= out projection + NCHW transpose =================
// 256 blocks x 32 tokens; wave = 16 rows x 128 cols; fp32 out (B,C,N).
__global__ __launch_bounds__(256) void outproj_kernel(const ushort* __restrict__ A,
                                                      const ushort* __restrict__ W,
                                                      const float* __restrict__ bias,
                                                      float* __restrict__ out) {
  __shared__ float ts[256][33];
  const int lane = threadIdx.x & 63;
  const int wvi = threadIdx.x >> 6;
  const int nlan = lane & 15, g = lane >> 4;
  const int rowgrp = wvi >> 1, colh = wvi & 1;
  const int r0b = blockIdx.x * 32;
  const int r0 = r0b + rowgrp * 16;

  f32x4 acc[8];
#pragma unroll
  for (int nt = 0; nt < 8; ++nt) acc[nt] = (f32x4){0.f, 0.f, 0.f, 0.f};

  const ushort* xp = A + (size_t)(r0 + nlan) * CDIM + g * 8;
  const ushort* wp = W + (size_t)(colh * 128 + nlan) * CDIM + g * 8;
#pragma unroll
  for (int k0 = 0; k0 < 8; ++k0) {
    const bf16x8 a = *reinterpret_cast<const bf16x8*>(xp + k0 * 32);
#pragma unroll
    for (int nt = 0; nt < 8; ++nt) {
      const bf16x8 bfr = *reinterpret_cast<const bf16x8*>(wp + (size_t)nt * 16 * CDIM + k0 * 32);
      acc[nt] = __builtin_amdgcn_mfma_f32_16x16x32_bf16(a, bfr, acc[nt], 0, 0, 0);
    }
  }

#pragma unroll
  for (int nt = 0; nt < 8; ++nt) {
    const int j = colh * 128 + nt * 16 + nlan;
    const float bj = bias[j];
#pragma unroll
    for (int reg = 0; reg < 4; ++reg)
      ts[j][rowgrp * 16 + 4 * g + reg] = acc[nt][reg] + bj;
  }
  __syncthreads();
  const int b = r0b >> 12;
  const int n0g = r0b & 4095;
#pragma unroll
  for (int k = 0; k < 32; ++k) {
    const int idx = k * 256 + threadIdx.x;
    const int cl = idx >> 5, tok = idx & 31;
    out[((size_t)b * CDIM + cl) * NTOK + n0g + tok] = ts[cl][tok];
  }
}

extern "C" void kernel_launch(void* const* d_in, const int* in_sizes, int n_in,
                              void* d_out, int out_size, void* d_ws, size_t ws_size,
                              hipStream_t stream) {
  (void)in_sizes; (void)n_in; (void)out_size; (void)ws_size;
  const float* q_feat  = (const float*)d_in[0];
  const float* kv_feat = (const float*)d_in[1];
  const float* nqw = (const float*)d_in[2];
  const float* nqb = (const float*)d_in[3];
  const float* nkw = (const float*)d_in[4];
  const float* nkb = (const float*)d_in[5];
  const float* wq  = (const float*)d_in[6];
  const float* bq  = (const float*)d_in[7];
  const float* wk  = (const float*)d_in[8];
  const float* bk  = (const float*)d_in[9];
  const float* wv  = (const float*)d_in[10];
  const float* bv  = (const float*)d_in[11];
  const float* wp  = (const float*)d_in[12];
  const float* bp  = (const float*)d_in[13];
  float* out = (float*)d_out;

  ushort* p = (ushort*)d_ws;
  ushort* wq_bf = p; p += 65536;
  ushort* wk_bf = p; p += 65536;
  ushort* wv_bf = p; p += 65536;
  ushort* wp_bf = p; p += 65536;
  ushort* Qp    = p; p += 8192 * 256;
  ushort* kvp   = p; p += 16 * 8 * 16 * 512;   // [bh][kc][tile][512] = 2MB
  ushort* aout  = p; p += 8192 * 256;

  prep_kernel<<<256, 256, 0, stream>>>(wq, wk, wv, wp, wq_bf, wk_bf, wv_bf, wp_bf);
  qkv_kernel<<<384, 256, 0, stream>>>(q_feat, kv_feat, nqw, nqb, nkw, nkb,
                                      wq_bf, wk_bf, wv_bf, bq, bk, bv, Qp, kvp);
  attn_kernel<<<dim3(64, 16), 128, 0, stream>>>(Qp, kvp, aout);
  outproj_kernel<<<256, 256, 0, stream>>>(aout, wp_bf, bp, out);
}

// Round 10
// 62.506 us; speedup vs baseline: 1.0171x; 1.0171x over previous
//
#include <hip/hip_runtime.h>

// CrossAttention MI355X — round 13: 4 waves/SIMD via PROVEN 4-wave blocks.
// R12's 8-wave/512-thread geometry raced (nondeterministic absmax); the
// single-q math itself is verified. Same TLP (4096 waves = 4/SIMD) with the
// R4/R7-verified 256-thread 4-wave block: grid (64,16), 16 q/wave, stage
// pattern byte-identical to R7 (wave wvi stages tiles wvi*4..+3).
// B=2, C=256, H=W=64 -> N=4096 q-tokens; kv pooled -> Nk=1024. HEADS=8, HDIM=32.

#define CDIM   256
#define NTOK   4096
#define NKTOK  1024
#define HDIM   32
// ATTN_SCALE * log2(e): exp(x*s) = 2^(x*s*log2e); fold into Q projection.
#define QSCALE 0.2550530290582177f
#define LN_EPS 1e-5f

typedef __attribute__((ext_vector_type(8))) short bf16x8;
typedef __attribute__((ext_vector_type(4))) float f32x4;
typedef __attribute__((ext_vector_type(4))) uint u32x4;

__device__ __forceinline__ ushort f2bf(float f) {
  uint u = __builtin_bit_cast(uint, f);
  u += 0x7fff + ((u >> 16) & 1);
  return (ushort)(u >> 16);
}

__device__ __forceinline__ float fast_exp2(float x) {
  float r;
  asm("v_exp_f32 %0, %1" : "=v"(r) : "v"(x));
  return r;
}

__device__ __forceinline__ uint cvt_pk_bf16(float lo, float hi) {
  uint r;
  asm("v_cvt_pk_bf16_f32 %0, %1, %2" : "=v"(r) : "v"(lo), "v"(hi));
  return r;
}

__device__ __forceinline__ void gload_lds16(const void* g, void* l) {
  __builtin_amdgcn_global_load_lds(
      (const __attribute__((address_space(1))) unsigned int*)g,
      (__attribute__((address_space(3))) unsigned int*)l, 16, 0, 0);
}

// ================= prep: weight fp32 -> bf16 only (256 blocks) =================
__global__ __launch_bounds__(256) void prep_kernel(
    const float* __restrict__ wq, const float* __restrict__ wk,
    const float* __restrict__ wvv, const float* __restrict__ wp,
    ushort* __restrict__ wq_bf, ushort* __restrict__ wk_bf,
    ushort* __restrict__ wv_bf, ushort* __restrict__ wp_bf) {
  const int bid = blockIdx.x;
  const int mat = bid >> 6;
  const int base = (bid & 63) * 1024 + threadIdx.x * 4;
  const float* s; ushort* d;
  switch (mat) {
    case 0: s = wq; d = wq_bf; break;
    case 1: s = wk; d = wk_bf; break;
    case 2: s = wvv; d = wv_bf; break;
    default: s = wp; d = wp_bf; break;
  }
  const float4 v = *reinterpret_cast<const float4*>(s + base);
  uint2 pk;
  pk.x = (uint)f2bf(v.x) | ((uint)f2bf(v.y) << 16);
  pk.y = (uint)f2bf(v.z) | ((uint)f2bf(v.w) << 16);
  *reinterpret_cast<uint2*>(d + base) = pk;
}

// ================= fused LN + QKV projection =================
// blocks: [0,256) Q (M=8192), [256,320) K (M=2048), [320,384) V (M=2048).
// Phase 1: block LNs its own 32 tokens (Q: plain LN; K/V: 2x2 avg-pool + LN)
//   into LDS xs[32][264] bf16. Phase 2: proven 4-wave MFMA loop; epilogue
//   identical to R4 (Qp scaled / kvp fragment-tile pack).
__global__ __launch_bounds__(256) void qkv_kernel(
    const float* __restrict__ q_feat, const float* __restrict__ kv_feat,
    const float* __restrict__ nqw, const float* __restrict__ nqb,
    const float* __restrict__ nkw, const float* __restrict__ nkb,
    const ushort* __restrict__ wq_bf, const ushort* __restrict__ wk_bf,
    const ushort* __restrict__ wv_bf,
    const float* __restrict__ bq, const float* __restrict__ bk,
    const float* __restrict__ bv,
    ushort* __restrict__ Qp, ushort* __restrict__ kvp) {
  __shared__ ushort xs[32][264];
  __shared__ float red[2][256];
  __shared__ float stat[2][32];

  const int bid = blockIdx.x;
  int seg, sb;
  const ushort* W; const float* bias;
  if (bid < 256)      { seg = 0; sb = bid;       W = wq_bf; bias = bq; }
  else if (bid < 320) { seg = 1; sb = bid - 256; W = wk_bf; bias = bk; }
  else                { seg = 2; sb = bid - 320; W = wv_bf; bias = bv; }

  const int tid = threadIdx.x;
  const int tok = tid & 31, cg = tid >> 5;      // 8 groups x 32 channels
  const int r0g = sb * 32;

  // ---- phase 1: LN / pool+LN of this block's 32 tokens -> xs ----
  float vals[32];
  float s = 0.f, ss = 0.f;
  if (seg == 0) {
    const int b = r0g >> 12;
    const int n = (r0g & 4095) + tok;
    const float* src = q_feat + (size_t)(b * CDIM + cg * 32) * NTOK + n;
#pragma unroll
    for (int ci = 0; ci < 32; ++ci) {
      const float v = src[(size_t)ci * NTOK];
      vals[ci] = v; s += v; ss = fmaf(v, v, ss);
    }
  } else {
    const int b = r0g >> 10;
    const int hk = (r0g & 1023) >> 5;           // 32 tokens/block -> hk uniform
    const float* src = kv_feat + (size_t)(b * CDIM + cg * 32) * NTOK + hk * 128 + tok * 2;
#pragma unroll
    for (int ci = 0; ci < 32; ++ci) {
      const float* p = src + (size_t)ci * NTOK;
      const float2 a0 = *reinterpret_cast<const float2*>(p);
      const float2 a1 = *reinterpret_cast<const float2*>(p + 64);
      const float v = 0.25f * ((a0.x + a0.y) + (a1.x + a1.y));
      vals[ci] = v; s += v; ss = fmaf(v, v, ss);
    }
  }
  red[0][tid] = s; red[1][tid] = ss;
  __syncthreads();
  if (tid < 32) {
    float st = 0.f, sst = 0.f;
#pragma unroll
    for (int k = 0; k < 8; ++k) { st += red[0][k * 32 + tid]; sst += red[1][k * 32 + tid]; }
    const float mu = st * (1.f / 256.f);
    const float var = sst * (1.f / 256.f) - mu * mu;
    stat[0][tid] = mu; stat[1][tid] = rsqrtf(var + LN_EPS);
  }
  __syncthreads();
  {
    const float mu = stat[0][tok], rs = stat[1][tok];
    const float* lw = (seg == 0) ? nqw : nkw;
    const float* lb = (seg == 0) ? nqb : nkb;
#pragma unroll
    for (int ci = 0; ci < 32; ci += 4) {
      ushort h[4];
#pragma unroll
      for (int j2 = 0; j2 < 4; ++j2) {
        const int c = cg * 32 + ci + j2;
        h[j2] = f2bf(fmaf((vals[ci + j2] - mu) * rs, lw[c], lb[c]));
      }
      uint2 pk2;
      pk2.x = (uint)h[0] | ((uint)h[1] << 16);
      pk2.y = (uint)h[2] | ((uint)h[3] << 16);
      *reinterpret_cast<uint2*>(&xs[tok][cg * 32 + ci]) = pk2;
    }
  }
  __syncthreads();

  // ---- phase 2: projection (proven MFMA loop; A from LDS) ----
  const int lane = tid & 63;
  const int wvi = tid >> 6;
  const int nlan = lane & 15, g = lane >> 4;
  const int rowgrp = wvi >> 1, colh = wvi & 1;
  const int lrow = rowgrp * 16 + nlan;
  const int r0 = r0g + rowgrp * 16;

  f32x4 acc[8];
#pragma unroll
  for (int nt = 0; nt < 8; ++nt) acc[nt] = (f32x4){0.f, 0.f, 0.f, 0.f};

  const ushort* wp = W + (size_t)(colh * 128 + nlan) * CDIM + g * 8;
#pragma unroll
  for (int k0 = 0; k0 < 8; ++k0) {
    const bf16x8 a = *reinterpret_cast<const bf16x8*>(&xs[lrow][g * 8 + k0 * 32]);
#pragma unroll
    for (int nt = 0; nt < 8; ++nt) {
      const bf16x8 bfr = *reinterpret_cast<const bf16x8*>(wp + (size_t)nt * 16 * CDIM + k0 * 32);
      acc[nt] = __builtin_amdgcn_mfma_f32_16x16x32_bf16(a, bfr, acc[nt], 0, 0, 0);
    }
  }

#pragma unroll
  for (int nt = 0; nt < 8; ++nt) {
    const int j = colh * 128 + nt * 16 + nlan;
    const float bj = bias[j];
#pragma unroll
    for (int reg = 0; reg < 4; ++reg) {
      const int r = r0 + 4 * g + reg;
      const float v = acc[nt][reg] + bj;
      if (seg == 0) {
        Qp[(size_t)r * CDIM + j] = f2bf(v * QSCALE);
      } else if (seg == 1) {
        // K -> pack. r = b*1024 + key, j = h*32 + d.
        const int bb = r >> 10, k = r & 1023;
        const int kc = k >> 7, kk = k & 127;
        const int m = kk >> 5, w = kk & 31;
        const int t = 2 * m + ((w >> 2) & 1);
        const int rr = ((w >> 3) << 2) | (w & 3);
        const int hh = j >> 5, d = j & 31;
        kvp[(((size_t)((bb * 8 + hh) * 8 + kc) * 16 + t) << 9) +
            ((d >> 3) * 16 + rr) * 8 + (d & 7)] = f2bf(v);
      } else {
        // V -> pack. r = b*1024 + key, j = h*32 + d.
        const int bb = r >> 10, mk = r & 1023;
        const int hh = j >> 5, d = j & 31;
        const int dt = d >> 4, rr = d & 15;
        const int kc = mk >> 7, km = mk & 127;
        const int ks = km >> 5, w = km & 31;
        const int gq = w >> 3, jj = w & 7;
        kvp[(((size_t)((bb * 8 + hh) * 8 + kc) * 16 + (8 + dt * 4 + ks)) << 9) +
            (gq * 16 + rr) * 8 + jj] = f2bf(v);
      }
    }
  }
}

// ================= attention =================
// grid (64, 16): x = 64-query tile (4 waves x 16 q), y = b*8+h. 256 threads.
// 1024 blocks x 4 waves = 4096 waves = 16/CU = 4 waves/SIMD (TLP doubled vs
// the 62µs baseline); 4 blocks/CU co-resident (LDS 32KB each, 128KB/CU).
// Per 128-key chunk: 16KB contiguous staged via global_load_lds from the
// pre-tiled kvp pack — stage pattern byte-identical to the verified R7 kernel
// (wave wvi stages tiles wvi*4..wvi*4+3; lane l -> tile base + l*16B).
// Swapped QK^T -> register softmax -> PV from registers (verified math):
// lane holds q=nlan; tiles 2m/2m+1 give keys 32m+8g+{0..7}; exp2 + 4x cvt_pk
// builds the 16x16x32 A-fragment P[q=nlan][k=8g+j] for PV.
__global__ __launch_bounds__(256) void attn_kernel(const ushort* __restrict__ Qp,
                                                   const ushort* __restrict__ kvp,
                                                   ushort* __restrict__ aout) {
  __shared__ __align__(16) ushort kvf[2][16][512];
  const int lane = threadIdx.x & 63;
  const int wvi = threadIdx.x >> 6;         // 0..3
  const int nlan = lane & 15, g = lane >> 4;
  const int bh = blockIdx.y;
  const int b = bh >> 3, h = bh & 7;
  const int n0 = blockIdx.x * 64 + wvi * 16;

  const bf16x8 qf = *reinterpret_cast<const bf16x8*>(
      Qp + (size_t)(b * NTOK + n0 + nlan) * CDIM + h * HDIM + g * 8);

  const ushort* kvb = kvp + ((size_t)bh << 16);   // 8 chunks x 16 tiles x 512

  auto stage = [&](int buf, int kc_idx) {
    const ushort* cb = kvb + ((size_t)kc_idx << 13);
#pragma unroll
    for (int i = 0; i < 4; ++i) {
      const int t = wvi * 4 + i;
      gload_lds16(cb + t * 512 + lane * 8, &kvf[buf][t][0]);
    }
  };

  f32x4 acc[2];
  acc[0] = (f32x4){0.f, 0.f, 0.f, 0.f};
  acc[1] = (f32x4){0.f, 0.f, 0.f, 0.f};
  float lsum = 0.f;
  const f32x4 zero = {0.f, 0.f, 0.f, 0.f};

  stage(0, 0);
  for (int c = 0; c < 8; ++c) {
    const int buf = c & 1;
    __syncthreads();                    // chunk c staged & visible
    if (c < 7) stage(buf ^ 1, c + 1);

#pragma unroll
    for (int m = 0; m < 4; ++m) {       // 32-key block
      uint pk[4];                       // 4 packed uints = keys 8g+0..7
#pragma unroll
      for (int half = 0; half < 2; ++half) {
        const bf16x8 kf = *reinterpret_cast<const bf16x8*>(&kvf[buf][2 * m + half][lane * 8]);
        const f32x4 s = __builtin_amdgcn_mfma_f32_16x16x32_bf16(kf, qf, zero, 0, 0, 0);
        const float p0 = fast_exp2(s[0]), p1 = fast_exp2(s[1]);
        const float p2 = fast_exp2(s[2]), p3 = fast_exp2(s[3]);
        lsum += (p0 + p1) + (p2 + p3);
        pk[half * 2 + 0] = cvt_pk_bf16(p0, p1);
        pk[half * 2 + 1] = cvt_pk_bf16(p2, p3);
      }
      const u32x4 w = {pk[0], pk[1], pk[2], pk[3]};
      const bf16x8 af = __builtin_bit_cast(bf16x8, w);
#pragma unroll
      for (int dt = 0; dt < 2; ++dt) {
        const bf16x8 vf = *reinterpret_cast<const bf16x8*>(&kvf[buf][8 + dt * 4 + m][lane * 8]);
        acc[dt] = __builtin_amdgcn_mfma_f32_16x16x32_bf16(af, vf, acc[dt], 0, 0, 0);
      }
    }
  }

  // lsum per lane covers q = nlan, keys {8g..8g+7} over all blocks; reduce over g.
  lsum += __shfl_xor(lsum, 16);
  lsum += __shfl_xor(lsum, 32);

  ushort* dst = aout + (size_t)(b * NTOK + n0) * CDIM + h * HDIM;
#pragma unroll
  for (int reg = 0; reg < 4; ++reg) {
    // acc row = q-row 4g+reg; its denominator lives at lane 4g+reg (nlan match).
    const float inv = 1.f / __shfl(lsum, 4 * g + reg);
    const size_t row = (size_t)(4 * g + reg) * CDIM;
    dst[row + nlan] = f2bf(acc[0][reg] * inv);
    dst[row + 16 + nlan] = f2bf(acc[1][reg] * inv);
  }
}

// ================= out projection + NCHW transpose =================
// 256 blocks x 32 tokens; wave = 16 rows x 128 cols; fp32 out (B,C,N).
__global__ __launch_bounds__(256) void outproj_kernel(const ushort* __restrict__ A,
                                                      const ushort* __restrict__ W,
                                                      const float* __restrict__ bias,
                                                      float* __restrict__ out) {
  __shared__ float ts[256][33];
  const int lane = threadIdx.x & 63;
  const int wvi = threadIdx.x >> 6;
  const int nlan = lane & 15, g = lane >> 4;
  const int rowgrp = wvi >> 1, colh = wvi & 1;
  const int r0b = blockIdx.x * 32;
  const int r0 = r0b + rowgrp * 16;

  f32x4 acc[8];
#pragma unroll
  for (int nt = 0; nt < 8; ++nt) acc[nt] = (f32x4){0.f, 0.f, 0.f, 0.f};

  const ushort* xp = A + (size_t)(r0 + nlan) * CDIM + g * 8;
  const ushort* wp = W + (size_t)(colh * 128 + nlan) * CDIM + g * 8;
#pragma unroll
  for (int k0 = 0; k0 < 8; ++k0) {
    const bf16x8 a = *reinterpret_cast<const bf16x8*>(xp + k0 * 32);
#pragma unroll
    for (int nt = 0; nt < 8; ++nt) {
      const bf16x8 bfr = *reinterpret_cast<const bf16x8*>(wp + (size_t)nt * 16 * CDIM + k0 * 32);
      acc[nt] = __builtin_amdgcn_mfma_f32_16x16x32_bf16(a, bfr, acc[nt], 0, 0, 0);
    }
  }

#pragma unroll
  for (int nt = 0; nt < 8; ++nt) {
    const int j = colh * 128 + nt * 16 + nlan;
    const float bj = bias[j];
#pragma unroll
    for (int reg = 0; reg < 4; ++reg)
      ts[j][rowgrp * 16 + 4 * g + reg] = acc[nt][reg] + bj;
  }
  __syncthreads();
  const int b = r0b >> 12;
  const int n0g = r0b & 4095;
#pragma unroll
  for (int k = 0; k < 32; ++k) {
    const int idx = k * 256 + threadIdx.x;
    const int cl = idx >> 5, tok = idx & 31;
    out[((size_t)b * CDIM + cl) * NTOK + n0g + tok] = ts[cl][tok];
  }
}

extern "C" void kernel_launch(void* const* d_in, const int* in_sizes, int n_in,
                              void* d_out, int out_size, void* d_ws, size_t ws_size,
                              hipStream_t stream) {
  (void)in_sizes; (void)n_in; (void)out_size; (void)ws_size;
  const float* q_feat  = (const float*)d_in[0];
  const float* kv_feat = (const float*)d_in[1];
  const float* nqw = (const float*)d_in[2];
  const float* nqb = (const float*)d_in[3];
  const float* nkw = (const float*)d_in[4];
  const float* nkb = (const float*)d_in[5];
  const float* wq  = (const float*)d_in[6];
  const float* bq  = (const float*)d_in[7];
  const float* wk  = (const float*)d_in[8];
  const float* bk  = (const float*)d_in[9];
  const float* wv  = (const float*)d_in[10];
  const float* bv  = (const float*)d_in[11];
  const float* wp  = (const float*)d_in[12];
  const float* bp  = (const float*)d_in[13];
  float* out = (float*)d_out;

  ushort* p = (ushort*)d_ws;
  ushort* wq_bf = p; p += 65536;
  ushort* wk_bf = p; p += 65536;
  ushort* wv_bf = p; p += 65536;
  ushort* wp_bf = p; p += 65536;
  ushort* Qp    = p; p += 8192 * 256;
  ushort* kvp   = p; p += 16 * 8 * 16 * 512;   // [bh][kc][tile][512] = 2MB
  ushort* aout  = p; p += 8192 * 256;

  prep_kernel<<<256, 256, 0, stream>>>(wq, wk, wv, wp, wq_bf, wk_bf, wv_bf, wp_bf);
  qkv_kernel<<<384, 256, 0, stream>>>(q_feat, kv_feat, nqw, nqb, nkw, nkb,
                                      wq_bf, wk_bf, wv_bf, bq, bk, bv, Qp, kvp);
  attn_kernel<<<dim3(64, 16), 256, 0, stream>>>(Qp, kvp, aout);
  outproj_kernel<<<256, 256, 0, stream>>>(aout, wp_bf, bp, out);
}